// Round 8
// baseline (823.434 us; speedup 1.0000x reference)
//
#include <hip/hip_runtime.h>
#include <stdint.h>

// FourierBlock: B=32, D=64, N=128, L=192, M=32 modes.
// ROUND 8 = MEASUREMENT ROUND. Kernels are r7-verbatim except each body is
// wrapped in an idempotent repeat loop (k1n x4, k2f x6, k3 x6) with compiler
// memory fences. This pushes every kernel above the harness's ~115us fill
// dispatches so all three appear in rocprof top-5 WITH counters.
// Per-iteration cost = dispatch_dur / REP. Outputs are bit-identical.
// ws: Xp 33.5MB @0, Yp 33.5MB @16777216 u16.

typedef __attribute__((ext_vector_type(8))) short short8;
typedef __attribute__((ext_vector_type(4))) float f32x4;
typedef __attribute__((ext_vector_type(4))) unsigned short u16x4;

#define REP_K1 4
#define REP_K2 6
#define REP_K3 6

__device__ __forceinline__ unsigned short f2bf(float f) {
  union { float fv; uint32_t u; } v; v.fv = f;
  uint32_t u = v.u;
  u += 0x7fffu + ((u >> 16) & 1u);          // round-to-nearest-even
  return (unsigned short)(u >> 16);
}

__device__ __forceinline__ f32x4 zero4() { f32x4 z; z[0]=0.f; z[1]=0.f; z[2]=0.f; z[3]=0.f; return z; }

#define TWO_PI_OVER_L (6.283185307179586f / 192.0f)

// ---------------------------------------------------------------------------
// K1n: DFT (r7 structure). grid 512 = (nq 32, bq 8, ih 2), 512 thr.
// ---------------------------------------------------------------------------
__global__ __launch_bounds__(512, 1)
void k1n_dft(const float* __restrict__ q, unsigned short* __restrict__ Xp) {
  extern __shared__ char smem[];
  float* qS = (float*)smem;
  unsigned short* Fb = (unsigned short*)(smem + 100352);
  unsigned short* XE = (unsigned short*)(smem + 125952);
  const int t = threadIdx.x, lane = t & 63, w = t >> 6;
  const int l15 = lane & 15, g = lane >> 4;
  const int bid = blockIdx.x;
  const int ih = bid & 1, bq = (bid >> 1) & 7, nq = bid >> 4;
  const int b0 = bq * 4;

  for (int idx = t; idx < 64 * 192; idx += 512) {
    int cat = idx / 192, l = idx - cat * 192;
    int m = cat >> 1;
    int r = (m * l) % 192;
    float ang = (float)r * TWO_PI_OVER_L;
    float v = (cat & 1) ? -__sinf(ang) : __cosf(ang);
    Fb[cat * 200 + l] = f2bf(v);
  }

  for (int rep = 0; rep < REP_K1; ++rep) {
    asm volatile("" ::: "memory");
    for (int nn = 0; nn < 4; ++nn) {
      const int n = nq * 4 + nn;

      float4 stg[12];
#pragma unroll
      for (int j = 0; j < 12; ++j) {
        int fq = (w * 12 + j) * 64 + lane;
        int row = fq / 48;
        int qd = fq - row * 48;
        int b = b0 + (row >> 5);
        int i = ih * 32 + (row & 31);
        stg[j] = *(const float4*)(q + ((size_t)((b * 64 + i) * 128 + n)) * 192 + qd * 4);
      }
#pragma unroll
      for (int j = 0; j < 12; ++j) {
        int fq = (w * 12 + j) * 64 + lane;
        int row = fq / 48;
        int qd = fq - row * 48;
        *(float4*)(qS + row * 196 + qd * 4) = stg[j];
      }
      __syncthreads();

      f32x4 acc[4];
#pragma unroll
      for (int a = 0; a < 4; ++a) acc[a] = zero4();

      const int row = w * 16 + l15;
#pragma unroll
      for (int kc = 0; kc < 6; ++kc) {
        f32x4 lo = *(const f32x4*)(qS + row * 196 + kc * 32 + g * 8);
        f32x4 hi = *(const f32x4*)(qS + row * 196 + kc * 32 + g * 8 + 4);
        short8 A;
        A[0] = (short)f2bf(lo[0]); A[1] = (short)f2bf(lo[1]);
        A[2] = (short)f2bf(lo[2]); A[3] = (short)f2bf(lo[3]);
        A[4] = (short)f2bf(hi[0]); A[5] = (short)f2bf(hi[1]);
        A[6] = (short)f2bf(hi[2]); A[7] = (short)f2bf(hi[3]);
#pragma unroll
        for (int nt = 0; nt < 4; ++nt) {
          short8 Bf = *(const short8*)(Fb + (nt * 16 + l15) * 200 + kc * 32 + g * 8);
          acc[nt] = __builtin_amdgcn_mfma_f32_16x16x32_bf16(A, Bf, acc[nt], 0, 0, 0);
        }
      }

      const int b_loc = w >> 1, i_base = (w & 1) * 16 + g * 4;
#pragma unroll
      for (int nt = 0; nt < 4; ++nt) {
        int cat = nt * 16 + l15;
        f32x4 v = acc[nt];
#pragma unroll
        for (int r = 0; r < 4; ++r)
          XE[cat * 128 + b_loc * 32 + i_base + r] = f2bf(v[r]);
      }
      __syncthreads();

#pragma unroll
      for (int cc2 = 0; cc2 < 2; ++cc2) {
        int ch = cc2 * 512 + t;
        int m = ch >> 5, c = (ch >> 4) & 1, g2 = (ch >> 2) & 3, dl = ch & 3;
        short8 v = *(const short8*)(XE + (2 * m + c) * 128 + dl * 32 + g2 * 8);
        int lanep = g2 * 16 + (b0 & 15) + dl;
        int off = n * 131072 + ((((m * 2 + c) * 2 + ih) * 2 + (b0 >> 4)) * 64 + lanep) * 8;
        *(short8*)(Xp + off) = v;
      }
      __syncthreads();
    }
  }
}

// ---------------------------------------------------------------------------
// K2f: fused W-stage + complex mix (r4/r7 structure). grid 512, 512 thr.
// ---------------------------------------------------------------------------
#define K2_OSTRIDE 34
#define K2_ISTRIDE 546        // 16*34 + 2
#define K2_CSTRIDE 34944      // 64*546
__global__ __launch_bounds__(512, 2)
void k2f_mix(const float* __restrict__ wr, const float* __restrict__ wi,
             const unsigned short* __restrict__ Xp, unsigned short* __restrict__ Yp) {
  extern __shared__ char smem[];
  unsigned short* T = (unsigned short*)smem;
  const int t = threadIdx.x, lane = t & 63, w = t >> 6;
  const int n = blockIdx.x >> 2, oq = blockIdx.x & 3;
  const int ol = lane & 15, il0 = (lane >> 4) * 8;

  for (int rep = 0; rep < REP_K2; ++rep) {
    asm volatile("" ::: "memory");
#pragma unroll
    for (int j = 0; j < 32; ++j) {
      int f = j * 512 + t;
      int mg = f & 7, o = (f >> 3) & 15, i = (f >> 7) & 63, c = (f >> 13) & 1;
      const float* src = (c ? wi : wr) + ((n * 64 + i) * 64 + oq * 16 + o) * 32 + mg * 4;
      float4 v = *(const float4*)src;
      u16x4 h; h[0] = f2bf(v.x); h[1] = f2bf(v.y); h[2] = f2bf(v.z); h[3] = f2bf(v.w);
      *(u16x4*)(T + c * K2_CSTRIDE + i * K2_ISTRIDE + o * K2_OSTRIDE + mg * 4) = h;
    }
    __syncthreads();

#pragma unroll
    for (int mm = 0; mm < 4; ++mm) {
      int m = w * 4 + mm;
      f32x4 acc[2][2];  // [cc][Mt]
#pragma unroll
      for (int a = 0; a < 2; ++a)
#pragma unroll
        for (int b2 = 0; b2 < 2; ++b2) acc[a][b2] = zero4();

#pragma unroll
      for (int ic = 0; ic < 2; ++ic) {
        const unsigned short* xb = Xp + n * 131072 + m * 4096 + ic * 1024 + lane * 8;
        short8 Ar0 = *(const short8*)(xb);
        short8 Ar1 = *(const short8*)(xb + 512);
        short8 Ai0 = *(const short8*)(xb + 2048);
        short8 Ai1 = *(const short8*)(xb + 2048 + 512);

        const unsigned short* tb = T + (ic * 32 + il0) * K2_ISTRIDE + ol * K2_OSTRIDE + m;
        short8 Br, Bi, nBi;
#pragma unroll
        for (int e = 0; e < 8; ++e) {
          Br[e] = (short)tb[e * K2_ISTRIDE];
          Bi[e] = (short)tb[K2_CSTRIDE + e * K2_ISTRIDE];
          nBi[e] = Bi[e] ^ (short)0x8000;   // -Wi
        }

        acc[0][0] = __builtin_amdgcn_mfma_f32_16x16x32_bf16(Ar0, Br,  acc[0][0], 0, 0, 0);
        acc[0][0] = __builtin_amdgcn_mfma_f32_16x16x32_bf16(Ai0, nBi, acc[0][0], 0, 0, 0);
        acc[0][1] = __builtin_amdgcn_mfma_f32_16x16x32_bf16(Ar1, Br,  acc[0][1], 0, 0, 0);
        acc[0][1] = __builtin_amdgcn_mfma_f32_16x16x32_bf16(Ai1, nBi, acc[0][1], 0, 0, 0);
        acc[1][0] = __builtin_amdgcn_mfma_f32_16x16x32_bf16(Ar0, Bi,  acc[1][0], 0, 0, 0);
        acc[1][0] = __builtin_amdgcn_mfma_f32_16x16x32_bf16(Ai0, Br,  acc[1][0], 0, 0, 0);
        acc[1][1] = __builtin_amdgcn_mfma_f32_16x16x32_bf16(Ar1, Bi,  acc[1][1], 0, 0, 0);
        acc[1][1] = __builtin_amdgcn_mfma_f32_16x16x32_bf16(Ai1, Br,  acc[1][1], 0, 0, 0);
      }

      const int g = lane >> 4;
#pragma unroll
      for (int cc = 0; cc < 2; ++cc) {
        int cat = 2 * m + cc;
#pragma unroll
        for (int Mt = 0; Mt < 2; ++Mt) {
          f32x4 v = acc[cc][Mt];
#pragma unroll
          for (int r = 0; r < 4; ++r) {
            int b = Mt * 16 + g * 4 + r;
            Yp[((n * 32 + b) * 64 + cat) * 64 + oq * 16 + ol] = f2bf(v[r]);
          }
        }
      }
    }
    __syncthreads();   // T dead before next rep's restage
  }
}

// ---------------------------------------------------------------------------
// K3: iDFT + transposed store (r4/r7 structure). grid 4096, 256 thr.
// ---------------------------------------------------------------------------
__global__ __launch_bounds__(256, 4)
void k3_idft(const unsigned short* __restrict__ Yp, float* __restrict__ out) {
  extern __shared__ char smem[];
  unsigned short* Yl = (unsigned short*)smem;
  float* ol = (float*)(smem + 8192);
  const int t = threadIdx.x, lane = t & 63, w = t >> 6;
  const int n = blockIdx.x & 127, b = blockIdx.x >> 7;

  for (int rep = 0; rep < REP_K3; ++rep) {
    asm volatile("" ::: "memory");
    const unsigned short* ysrc = Yp + (n * 32 + b) * 4096;
#pragma unroll
    for (int j = 0; j < 2; ++j) {
      int f = j * 256 + t;
      *(short8*)(Yl + f * 8) = *(const short8*)(ysrc + f * 8);
    }

    short8 Af[3][2];
#pragma unroll
    for (int jm = 0; jm < 3; ++jm) {
      int Mt = w + 4 * jm;
      int lt = Mt * 16 + (lane & 15);
#pragma unroll
      for (int kc = 0; kc < 2; ++kc) {
#pragma unroll
        for (int e = 0; e < 8; ++e) {
          int cat = kc * 32 + (lane >> 4) * 8 + e;
          int m = cat >> 1;
          int r = (m * lt) % 192;
          float ang = (float)r * TWO_PI_OVER_L;
          float coef = (m == 0) ? (1.0f / 192.0f) : (2.0f / 192.0f);
          float v = ((cat & 1) ? -__sinf(ang) : __cosf(ang)) * coef;
          Af[jm][kc][e] = (short)f2bf(v);
        }
      }
    }
    __syncthreads();

    f32x4 acc[3][4];
#pragma unroll
    for (int a = 0; a < 3; ++a)
#pragma unroll
      for (int bq = 0; bq < 4; ++bq) acc[a][bq] = zero4();

#pragma unroll
    for (int kc = 0; kc < 2; ++kc) {
      short8 Bf[4];
#pragma unroll
      for (int nt = 0; nt < 4; ++nt)
#pragma unroll
        for (int e = 0; e < 8; ++e) {
          int cat = kc * 32 + (lane >> 4) * 8 + e;
          Bf[nt][e] = (short)Yl[cat * 64 + nt * 16 + (lane & 15)];
        }
#pragma unroll
      for (int jm = 0; jm < 3; ++jm)
#pragma unroll
        for (int nt = 0; nt < 4; ++nt)
          acc[jm][nt] = __builtin_amdgcn_mfma_f32_16x16x32_bf16(Af[jm][kc], Bf[nt], acc[jm][nt], 0, 0, 0);
    }

#pragma unroll
    for (int jm = 0; jm < 3; ++jm) {
      int Mt = w + 4 * jm;
      int l0 = Mt * 16 + (lane >> 4) * 4;
#pragma unroll
      for (int nt = 0; nt < 4; ++nt) {
        int o = nt * 16 + (lane & 15);
        int lp = l0 ^ ((o & 7) << 2);
        *(f32x4*)(ol + o * 192 + lp) = acc[jm][nt];
      }
    }
    __syncthreads();

    float* dst = out + (b * 64 * 128 + n) * 192;
#pragma unroll
    for (int j = 0; j < 12; ++j) {
      int f = j * 256 + t;
      int o = f / 48, g2 = f - o * 48;
      int lp = g2 * 4;
      int l = lp ^ ((o & 7) << 2);
      f32x4 v = *(const f32x4*)(ol + o * 192 + lp);
      *(f32x4*)(dst + o * (128 * 192) + l) = v;
    }
    __syncthreads();   // Yl/ol dead before next rep
  }
}

// ---------------------------------------------------------------------------
extern "C" void kernel_launch(void* const* d_in, const int* in_sizes, int n_in,
                              void* d_out, int out_size, void* d_ws, size_t ws_size,
                              hipStream_t stream) {
  const float* q  = (const float*)d_in[0];
  const float* wr = (const float*)d_in[1];
  const float* wi = (const float*)d_in[2];
  float* out = (float*)d_out;

  unsigned short* Xp = (unsigned short*)d_ws;            // 33.5 MB
  unsigned short* Yp = Xp + 16777216;                    // 33.5 MB

  hipFuncSetAttribute((const void*)k1n_dft, hipFuncAttributeMaxDynamicSharedMemorySize, 142336);
  hipFuncSetAttribute((const void*)k2f_mix, hipFuncAttributeMaxDynamicSharedMemorySize, 139776);
  hipFuncSetAttribute((const void*)k3_idft, hipFuncAttributeMaxDynamicSharedMemorySize, 57344);

  k1n_dft<<<dim3(512), dim3(512), 142336, stream>>>(q, Xp);
  k2f_mix<<<dim3(512), dim3(512), 139776, stream>>>(wr, wi, Xp, Yp);
  k3_idft<<<dim3(4096), dim3(256), 57344, stream>>>(Yp, out);
}

// Round 9
// 218.293 us; speedup vs baseline: 3.7721x; 3.7721x over previous
//
#include <hip/hip_runtime.h>
#include <stdint.h>

// FourierBlock: B=32, D=64, N=128, L=192, M=32 modes.
// Round 9: streaming restructure per r8 attribution (k1~97, k2f~66, k3~30;
// law: barrier-phased 1-blk/CU kernels ~2-3.8 TB/s, streaming ~5-7 TB/s).
//   k1s: DFT as pure streaming GEMM over q viewed as [262144 rows][192] fp32
//        (row=(b*64+i)*128+n). A-frags direct from global, F in 26KB LDS
//        (cos-table build), 6 blk/CU. Writes X1[row][cat] coalesced.
//   k1t: X1 -> Xp frag-pack transpose. 16 reg-batched strided loads (deep MLP),
//        LDS 66KB, 2 blk/CU. 134 MB.
//   k2h: k2f with i-split staging: LDS 69.9KB -> 2 blk/CU, acc across halves,
//        A-frags once, reg-batched stage. Yp layout unchanged.
//   k3:  r4 verbatim.
// ws: Xp 33.5MB @0, Yp 33.5MB @16777216 u16, X1 33.5MB @33554432 u16.

typedef __attribute__((ext_vector_type(8))) short short8;
typedef __attribute__((ext_vector_type(4))) float f32x4;
typedef __attribute__((ext_vector_type(4))) unsigned short u16x4;

__device__ __forceinline__ unsigned short f2bf(float f) {
  union { float fv; uint32_t u; } v; v.fv = f;
  uint32_t u = v.u;
  u += 0x7fffu + ((u >> 16) & 1u);          // round-to-nearest-even
  return (unsigned short)(u >> 16);
}

__device__ __forceinline__ f32x4 zero4() { f32x4 z; z[0]=0.f; z[1]=0.f; z[2]=0.f; z[3]=0.f; return z; }

#define TWO_PI_OVER_L (6.283185307179586f / 192.0f)

// ---------------------------------------------------------------------------
// k1s: streaming DFT. grid 2048, 256 thr (4 waves), LDS 26368 B -> 6 blk/CU.
// Each wave: 2 tiles of 16 rows; rows are n-consecutive (contiguous in q).
// A direct-from-global (16 rows x 128B per kc, full-line coverage), B from F.
// C stored to X1[row][cat] (u16 scalar, 32B runs).
// ---------------------------------------------------------------------------
__global__ __launch_bounds__(256, 4)
void k1s_dft(const float* __restrict__ q, unsigned short* __restrict__ X1) {
  extern __shared__ char smem[];
  float* costab = (float*)smem;                        // 192 f32 = 768 B
  unsigned short* Fb = (unsigned short*)(smem + 768);  // [64 cat][200]
  const int t = threadIdx.x, lane = t & 63, w = t >> 6;
  const int l15 = lane & 15, g = lane >> 4;

  for (int j = t; j < 192; j += 256)
    costab[j] = __cosf((float)j * TWO_PI_OVER_L);
  __syncthreads();
  // F[cat][l]: c=0 -> cos(2pi*m*l/192), c=1 -> -sin = cos(+48 steps)
  for (int idx = t; idx < 64 * 192; idx += 256) {
    int cat = idx / 192, l = idx - cat * 192;
    int m = cat >> 1;
    int r = (m * l) % 192;
    if (cat & 1) { r += 48; if (r >= 192) r -= 192; }
    Fb[cat * 200 + l] = f2bf(costab[r]);
  }
  __syncthreads();

  for (int rr = 0; rr < 2; ++rr) {
    const int row0 = blockIdx.x * 128 + w * 32 + rr * 16;
    f32x4 acc[4];
#pragma unroll
    for (int a = 0; a < 4; ++a) acc[a] = zero4();

    const float* qrow = q + (size_t)(row0 + l15) * 192;
#pragma unroll
    for (int kc = 0; kc < 6; ++kc) {
      float4 lo = *(const float4*)(qrow + kc * 32 + g * 8);
      float4 hi = *(const float4*)(qrow + kc * 32 + g * 8 + 4);
      short8 A;
      A[0] = (short)f2bf(lo.x); A[1] = (short)f2bf(lo.y);
      A[2] = (short)f2bf(lo.z); A[3] = (short)f2bf(lo.w);
      A[4] = (short)f2bf(hi.x); A[5] = (short)f2bf(hi.y);
      A[6] = (short)f2bf(hi.z); A[7] = (short)f2bf(hi.w);
#pragma unroll
      for (int nt = 0; nt < 4; ++nt) {
        short8 Bf = *(const short8*)(Fb + (nt * 16 + l15) * 200 + kc * 32 + g * 8);
        acc[nt] = __builtin_amdgcn_mfma_f32_16x16x32_bf16(A, Bf, acc[nt], 0, 0, 0);
      }
    }
    // C: col cat = nt*16+l15, row = row0 + g*4 + r
#pragma unroll
    for (int nt = 0; nt < 4; ++nt) {
      f32x4 v = acc[nt];
#pragma unroll
      for (int r = 0; r < 4; ++r)
        X1[(size_t)(row0 + g * 4 + r) * 64 + nt * 16 + l15] = f2bf(v[r]);
    }
  }
}

// ---------------------------------------------------------------------------
// k1t: X1 -> Xp frag-pack. grid 512 = (n128, Mt2 2, ih 2), 256 thr, LDS 67584.
// 16 reg-batched 16B loads (16KB-strided gather, 128KB/CU in flight) ->
// T[row=i5*16+b][66] -> per-(cat) gather -> contiguous 16B Xp stores.
// Xp[n][cat][ih][Mt2][lane][e] = X[b=Mt2*16+(lane&15)][i=ih*32+(lane>>4)*8+e].
// ---------------------------------------------------------------------------
__global__ __launch_bounds__(256, 2)
void k1t_pack(const unsigned short* __restrict__ X1, unsigned short* __restrict__ Xp) {
  extern __shared__ char smem[];
  unsigned short* T = (unsigned short*)smem;           // [512 rows][66]
  const int t = threadIdx.x;
  const int bid = blockIdx.x;
  const int ih = bid & 1, Mt2 = (bid >> 1) & 1, n = bid >> 2;
  const int i5 = t >> 3, c8 = t & 7;

  // batch all 16 b-runs into regs (64 VGPR), then write LDS
  short8 rbuf[16];
#pragma unroll
  for (int b = 0; b < 16; ++b) {
    size_t row = (size_t)(((Mt2 * 16 + b) * 64) + ih * 32 + i5) * 128 + n;
    rbuf[b] = *(const short8*)(X1 + row * 64 + c8 * 8);
  }
#pragma unroll
  for (int b = 0; b < 16; ++b)
    *(short8*)(T + (i5 * 16 + b) * 66 + c8 * 8) = rbuf[b];
  __syncthreads();

  // gather per (cat): lane s -> b15=s&15, g=s>>4; e -> i5 = g*8+e
#pragma unroll
  for (int j = 0; j < 16; ++j) {
    int f = j * 256 + t;
    int cat = f >> 6, s = f & 63;
    int b15 = s & 15, gg = s >> 4;
    short8 v;
#pragma unroll
    for (int e = 0; e < 8; ++e)
      v[e] = (short)T[((gg * 8 + e) * 16 + b15) * 66 + cat];
    *(short8*)(Xp + n * 131072 + cat * 2048 + ih * 1024 + Mt2 * 512 + s * 8) = v;
  }
}

// ---------------------------------------------------------------------------
// k2h: complex mix, i-split staging. grid 512 = (n, oq), 512 thr, LDS 69888 B
// -> 2 blk/CU (stage of one block overlaps compute of the other).
// T[c2][i32][o16][m32]: c-stride 17472, i-stride 546, o-stride 34 (u16).
// acc[4 mm][2 cc][2 Mt] persists across i-halves; A-frags read once each.
// ---------------------------------------------------------------------------
__global__ __launch_bounds__(512, 4)
void k2h_mix(const float* __restrict__ wr, const float* __restrict__ wi,
             const unsigned short* __restrict__ Xp, unsigned short* __restrict__ Yp) {
  extern __shared__ char smem[];
  unsigned short* T = (unsigned short*)smem;
  const int t = threadIdx.x, lane = t & 63, w = t >> 6;
  const int n = blockIdx.x >> 2, oq = blockIdx.x & 3;
  const int ol = lane & 15, il0 = (lane >> 4) * 8, g = lane >> 4;

  f32x4 acc[4][2][2];   // [mm][cc][Mt]
#pragma unroll
  for (int a = 0; a < 4; ++a)
#pragma unroll
    for (int c2 = 0; c2 < 2; ++c2)
#pragma unroll
      for (int b2 = 0; b2 < 2; ++b2) acc[a][c2][b2] = zero4();

  for (int ic = 0; ic < 2; ++ic) {
    if (ic) __syncthreads();               // compute(ic-1) done before restage
    // stage W[n][ic*32+i][oq*16+o][m] both c: 8192 float4 / 512 thr = 16/thr,
    // reg-batched 4 at a time
#pragma unroll
    for (int jb = 0; jb < 4; ++jb) {
      float4 s[4];
#pragma unroll
      for (int k = 0; k < 4; ++k) {
        int f = (jb * 4 + k) * 512 + t;
        int mg = f & 7, o = (f >> 3) & 15, i = (f >> 7) & 31, c = (f >> 12) & 1;
        s[k] = *(const float4*)((c ? wi : wr) +
                ((n * 64 + ic * 32 + i) * 64 + oq * 16 + o) * 32 + mg * 4);
      }
#pragma unroll
      for (int k = 0; k < 4; ++k) {
        int f = (jb * 4 + k) * 512 + t;
        int mg = f & 7, o = (f >> 3) & 15, i = (f >> 7) & 31, c = (f >> 12) & 1;
        u16x4 h; h[0] = f2bf(s[k].x); h[1] = f2bf(s[k].y); h[2] = f2bf(s[k].z); h[3] = f2bf(s[k].w);
        *(u16x4*)(T + c * 17472 + i * 546 + o * 34 + mg * 4) = h;
      }
    }
    __syncthreads();

#pragma unroll
    for (int mm = 0; mm < 4; ++mm) {
      int m = w * 4 + mm;
      // A-frags (read once per (m,ic)): coalesced 1KB loads
      const unsigned short* xb = Xp + n * 131072 + m * 4096 + ic * 1024 + lane * 8;
      short8 Ar0 = *(const short8*)(xb);
      short8 Ar1 = *(const short8*)(xb + 512);
      short8 Ai0 = *(const short8*)(xb + 2048);
      short8 Ai1 = *(const short8*)(xb + 2048 + 512);

      const unsigned short* tb = T + il0 * 546 + ol * 34 + m;
      short8 Br, Bi, nBi;
#pragma unroll
      for (int e = 0; e < 8; ++e) {
        Br[e] = (short)tb[e * 546];
        Bi[e] = (short)tb[17472 + e * 546];
        nBi[e] = Bi[e] ^ (short)0x8000;   // -Wi
      }

      acc[mm][0][0] = __builtin_amdgcn_mfma_f32_16x16x32_bf16(Ar0, Br,  acc[mm][0][0], 0, 0, 0);
      acc[mm][0][0] = __builtin_amdgcn_mfma_f32_16x16x32_bf16(Ai0, nBi, acc[mm][0][0], 0, 0, 0);
      acc[mm][0][1] = __builtin_amdgcn_mfma_f32_16x16x32_bf16(Ar1, Br,  acc[mm][0][1], 0, 0, 0);
      acc[mm][0][1] = __builtin_amdgcn_mfma_f32_16x16x32_bf16(Ai1, nBi, acc[mm][0][1], 0, 0, 0);
      acc[mm][1][0] = __builtin_amdgcn_mfma_f32_16x16x32_bf16(Ar0, Bi,  acc[mm][1][0], 0, 0, 0);
      acc[mm][1][0] = __builtin_amdgcn_mfma_f32_16x16x32_bf16(Ai0, Br,  acc[mm][1][0], 0, 0, 0);
      acc[mm][1][1] = __builtin_amdgcn_mfma_f32_16x16x32_bf16(Ar1, Bi,  acc[mm][1][1], 0, 0, 0);
      acc[mm][1][1] = __builtin_amdgcn_mfma_f32_16x16x32_bf16(Ai1, Br,  acc[mm][1][1], 0, 0, 0);
    }
  }

  // epilogue: Yp[n][b][2m+cc][oq*16+ol]  (r4 pattern)
#pragma unroll
  for (int mm = 0; mm < 4; ++mm) {
    int m = w * 4 + mm;
#pragma unroll
    for (int cc = 0; cc < 2; ++cc) {
      int cat = 2 * m + cc;
#pragma unroll
      for (int Mt = 0; Mt < 2; ++Mt) {
        f32x4 v = acc[mm][cc][Mt];
#pragma unroll
        for (int r = 0; r < 4; ++r) {
          int b = Mt * 16 + g * 4 + r;
          Yp[((n * 32 + b) * 64 + cat) * 64 + oq * 16 + ol] = f2bf(v[r]);
        }
      }
    }
  }
}

// ---------------------------------------------------------------------------
// K3: iDFT + transposed store. grid 4096 = (b 32, n 128), 256 thr. (r4 VERBATIM)
// ---------------------------------------------------------------------------
__global__ __launch_bounds__(256, 4)
void k3_idft(const unsigned short* __restrict__ Yp, float* __restrict__ out) {
  extern __shared__ char smem[];
  unsigned short* Yl = (unsigned short*)smem;
  float* ol = (float*)(smem + 8192);
  const int t = threadIdx.x, lane = t & 63, w = t >> 6;
  const int n = blockIdx.x & 127, b = blockIdx.x >> 7;

  const unsigned short* ysrc = Yp + (n * 32 + b) * 4096;
#pragma unroll
  for (int j = 0; j < 2; ++j) {
    int f = j * 256 + t;
    *(short8*)(Yl + f * 8) = *(const short8*)(ysrc + f * 8);
  }

  short8 Af[3][2];
#pragma unroll
  for (int jm = 0; jm < 3; ++jm) {
    int Mt = w + 4 * jm;
    int lt = Mt * 16 + (lane & 15);
#pragma unroll
    for (int kc = 0; kc < 2; ++kc) {
#pragma unroll
      for (int e = 0; e < 8; ++e) {
        int cat = kc * 32 + (lane >> 4) * 8 + e;
        int m = cat >> 1;
        int r = (m * lt) % 192;
        float ang = (float)r * TWO_PI_OVER_L;
        float coef = (m == 0) ? (1.0f / 192.0f) : (2.0f / 192.0f);
        float v = ((cat & 1) ? -__sinf(ang) : __cosf(ang)) * coef;
        Af[jm][kc][e] = (short)f2bf(v);
      }
    }
  }
  __syncthreads();

  f32x4 acc[3][4];
#pragma unroll
  for (int a = 0; a < 3; ++a)
#pragma unroll
    for (int bq = 0; bq < 4; ++bq) acc[a][bq] = zero4();

#pragma unroll
  for (int kc = 0; kc < 2; ++kc) {
    short8 Bf[4];
#pragma unroll
    for (int nt = 0; nt < 4; ++nt)
#pragma unroll
      for (int e = 0; e < 8; ++e) {
        int cat = kc * 32 + (lane >> 4) * 8 + e;
        Bf[nt][e] = (short)Yl[cat * 64 + nt * 16 + (lane & 15)];
      }
#pragma unroll
    for (int jm = 0; jm < 3; ++jm)
#pragma unroll
      for (int nt = 0; nt < 4; ++nt)
        acc[jm][nt] = __builtin_amdgcn_mfma_f32_16x16x32_bf16(Af[jm][kc], Bf[nt], acc[jm][nt], 0, 0, 0);
  }

#pragma unroll
  for (int jm = 0; jm < 3; ++jm) {
    int Mt = w + 4 * jm;
    int l0 = Mt * 16 + (lane >> 4) * 4;
#pragma unroll
    for (int nt = 0; nt < 4; ++nt) {
      int o = nt * 16 + (lane & 15);
      int lp = l0 ^ ((o & 7) << 2);
      *(f32x4*)(ol + o * 192 + lp) = acc[jm][nt];
    }
  }
  __syncthreads();

  float* dst = out + (b * 64 * 128 + n) * 192;
#pragma unroll
  for (int j = 0; j < 12; ++j) {
    int f = j * 256 + t;
    int o = f / 48, g2 = f - o * 48;
    int lp = g2 * 4;
    int l = lp ^ ((o & 7) << 2);
    f32x4 v = *(const f32x4*)(ol + o * 192 + lp);
    *(f32x4*)(dst + o * (128 * 192) + l) = v;
  }
}

// ---------------------------------------------------------------------------
extern "C" void kernel_launch(void* const* d_in, const int* in_sizes, int n_in,
                              void* d_out, int out_size, void* d_ws, size_t ws_size,
                              hipStream_t stream) {
  const float* q  = (const float*)d_in[0];
  const float* wr = (const float*)d_in[1];
  const float* wi = (const float*)d_in[2];
  float* out = (float*)d_out;

  unsigned short* Xp = (unsigned short*)d_ws;            // 33.5 MB
  unsigned short* Yp = Xp + 16777216;                    // 33.5 MB
  unsigned short* X1 = Xp + 33554432;                    // 33.5 MB

  hipFuncSetAttribute((const void*)k1s_dft, hipFuncAttributeMaxDynamicSharedMemorySize, 26368);
  hipFuncSetAttribute((const void*)k1t_pack, hipFuncAttributeMaxDynamicSharedMemorySize, 67584);
  hipFuncSetAttribute((const void*)k2h_mix, hipFuncAttributeMaxDynamicSharedMemorySize, 69888);
  hipFuncSetAttribute((const void*)k3_idft, hipFuncAttributeMaxDynamicSharedMemorySize, 57344);

  k1s_dft<<<dim3(2048), dim3(256), 26368, stream>>>(q, X1);
  k1t_pack<<<dim3(512), dim3(256), 67584, stream>>>(X1, Xp);
  k2h_mix<<<dim3(512), dim3(512), 69888, stream>>>(wr, wi, Xp, Yp);
  k3_idft<<<dim3(4096), dim3(256), 57344, stream>>>(Yp, out);
}